// Round 7
// baseline (115.757 us; speedup 1.0000x reference)
//
#include <hip/hip_runtime.h>
#include <math.h>

#define N_AGENTS 1024
#define HIDDEN   128
#define GRIDSZ   32
#define NCELLS   1024
#define KDIM     2048
#define NBLOCKS  64
#define MAGIC    0x5CADE50u

typedef __attribute__((ext_vector_type(8))) short short8;   // 8 bf16 = 4 VGPRs
typedef __attribute__((ext_vector_type(4))) float floatx4;  // MFMA accumulator

static __device__ __forceinline__ ushort f2bf(float x) {   // RNE fp32->bf16
    union { float f; unsigned u; } v; v.f = x;
    return (ushort)((v.u + 0x7fffu + ((v.u >> 16) & 1u)) >> 16);
}

// One block per 16-agent m-tile (64 blocks x 1024 thr). Every block is also a
// producer of 1/64 of Sh and bf16 W; consumers acquire via per-block flags.
// Scan+pooling once per m-tile (was 4x in R6); MFMA over all 128 cols.
__global__ __launch_bounds__(1024, 1) void k_one(
        const float* __restrict__ hidden, const float* __restrict__ obs2,
        const float* __restrict__ W, const float* __restrict__ bias,
        float* __restrict__ out,
        float* __restrict__ Sh, ushort* __restrict__ Wb,
        unsigned* __restrict__ flags) {
    __shared__ float2 spos[N_AGENTS];                   // 8 KB
    __shared__ float4 ssh[N_AGENTS];                    // 16 KB
    __shared__ int win[16][NCELLS];                     // 64 KB (reused as pbuf)
    __shared__ __align__(16) ushort Gs[256 * 16 * 8];   // 64 KB: [kblk][row][8] bf16

    const int tid = threadIdx.x;
    const int mt = blockIdx.x;
    const int ibase = mt * 16;

    // ---- P-1: producer slice — W cvt (4096 elems) + Sh for our 16 agents
    {
        float4 w = ((const float4*)W)[mt * 1024 + tid];
        ushort4 u;
        u.x = f2bf(w.x); u.y = f2bf(w.y); u.z = f2bf(w.z); u.w = f2bf(w.w);
        *(ushort4*)(Wb + (size_t)(mt * 1024 + tid) * 4) = u;
    }
    if (tid < 64) {
        int j = ibase + (tid >> 2), c = tid & 3;
        const float* h = hidden + j * HIDDEN + c * 8;
        float s = 0.f;
#pragma unroll
        for (int u = 0; u < 4; ++u) {
            float4 a = *(const float4*)(h + u * 32);
            float4 b = *(const float4*)(h + u * 32 + 4);
            s += a.x + a.y + a.z + a.w + b.x + b.y + b.z + b.w;
        }
        Sh[j * 4 + c] = s;
    }
    __threadfence();
    __syncthreads();
    if (tid == 0)
        __hip_atomic_store(&flags[mt], MAGIC, __ATOMIC_RELEASE, __HIP_MEMORY_SCOPE_AGENT);

    // ---- P0: positions + winner-grid init
    spos[tid] = ((const float2*)obs2)[tid];
    {
        int4* wl = (int4*)&win[0][0];
        int4 m1 = {-1, -1, -1, -1};
#pragma unroll
        for (int q = 0; q < 4; ++q) wl[q * 1024 + tid] = m1;
    }
    __syncthreads();

    // ---- P1: one j-scan fills 16 winner grids (set semantics == max j)
    float2 pi[16];
#pragma unroll
    for (int a = 0; a < 16; ++a) pi[a] = spos[ibase + a];
    {
        float2 pj = spos[tid];   // thread == j
        if (!isnan(pj.x)) {
#pragma unroll
            for (int a = 0; a < 16; ++a) {
                if (tid == ibase + a) continue;
                // exact reference fp32 math: /0.125 == *8 (exact pow2), then +16
                float rx = (pj.x - pi[a].x) * 8.0f + 16.0f;   // NaN pi -> cmps false
                float ry = (pj.y - pi[a].y) * 8.0f + 16.0f;
                if (rx >= 0.f && rx < 32.f && ry >= 0.f && ry < 32.f)
                    atomicMax(&win[a][(int)rx * GRIDSZ + (int)ry], tid);
            }
        }
    }
    __syncthreads();

    // ---- spin: every wave acquires all 64 producer flags (usually already set)
    {
        int lane = tid & 63;
        while (__hip_atomic_load(&flags[lane], __ATOMIC_ACQUIRE,
                                 __HIP_MEMORY_SCOPE_AGENT) != MAGIC) {}
    }
    ssh[tid] = ((const float4*)Sh)[tid];
    __syncthreads();

    // ---- P2: pooling -> bf16 A-tile in LDS, layout [kblk=k/8][row=a][8 elems]
#pragma unroll
    for (int q = 0; q < 8; ++q) {
        int task = q * 1024 + tid;
        int a = task & 15, p = task >> 4;   // cell-pair p, local agent a
        int w0 = win[a][2 * p], w1 = win[a][2 * p + 1];
        float4 v = {0.f, 0.f, 0.f, 0.f};
        if (w0 >= 0) { float4 s = ssh[w0]; v.x += s.x; v.y += s.y; v.z += s.z; v.w += s.w; }
        if (w1 >= 0) { float4 s = ssh[w1]; v.x += s.x; v.y += s.y; v.z += s.z; v.w += s.w; }
        ushort4 u;
        u.x = f2bf(v.x); u.y = f2bf(v.y); u.z = f2bf(v.z); u.w = f2bf(v.w);
        // k = 4p + [0..3]  ->  kblk = p>>1, e = (p&1)*4 + [0..3]
        *(ushort4*)(Gs + ((p >> 1) * 16 + a) * 8 + (p & 1) * 4) = u;
    }
    __syncthreads();

    // ---- P3: MFMA. wave w: n-tile ntl = w>>1, k-splits {ks2, ks2+1} summed
    // in-register. A from LDS Gs, B = bf16 W straight from L2.
    const int wv = tid >> 6, lane = tid & 63;
    const int ntl = wv >> 1, ks2 = (wv & 1) * 2;
    const int r16 = lane & 15, quad = lane >> 4;
    const int col = ntl * 16 + r16;
    floatx4 accs = {0.f, 0.f, 0.f, 0.f};
#pragma unroll
    for (int kh = 0; kh < 2; ++kh) {
        const int ks = ks2 + kh;
        const ushort* Wp = Wb + (size_t)col * KDIM + ks * 512 + quad * 8;
        floatx4 acc = {0.f, 0.f, 0.f, 0.f};
#pragma unroll
        for (int kb = 0; kb < 16; ++kb) {
            short8 av = *(const short8*)(Gs + ((ks * 64 + kb * 4 + quad) * 16 + r16) * 8);
            short8 bv = *(const short8*)(Wp + kb * 32);
            acc = __builtin_amdgcn_mfma_f32_16x16x32_bf16(av, bv, acc, 0, 0, 0);
        }
        accs[0] += acc[0]; accs[1] += acc[1]; accs[2] += acc[2]; accs[3] += acc[3];
    }

    // ---- P4: 2-way cross-wave k-reduce (pbuf aliases dead win), bias, store
    float* pbuf = (float*)&win[0][0];   // 16 KB used
    *(floatx4*)&pbuf[tid * 4] = accs;
    __syncthreads();
    if ((wv & 1) == 0) {
        floatx4 pv = *(const floatx4*)&pbuf[((wv + 1) * 64 + lane) * 4];
        accs[0] += pv[0]; accs[1] += pv[1]; accs[2] += pv[2]; accs[3] += pv[3];
        float bc = bias[col];
        // C/D layout (m89-verified): col = lane&15, row = quad*4 + reg
#pragma unroll
        for (int r = 0; r < 4; ++r)
            out[(size_t)(ibase + quad * 4 + r) * HIDDEN + col] = accs[r] + bc;
    }
}

extern "C" void kernel_launch(void* const* d_in, const int* in_sizes, int n_in,
                              void* d_out, int out_size, void* d_ws, size_t ws_size,
                              hipStream_t stream) {
    const float* hidden = (const float*)d_in[0];
    // d_in[1] = obs1 — unused by the reference
    const float* obs2   = (const float*)d_in[2];
    const float* W      = (const float*)d_in[3];
    const float* b      = (const float*)d_in[4];
    float* out = (float*)d_out;

    float*    Sh    = (float*)   d_ws;                       // 16 KB
    ushort*   Wb    = (ushort*)  ((char*)d_ws + 65536);      // 512 KB bf16 W
    unsigned* flags = (unsigned*)((char*)d_ws + (1u << 20)); // 64 words (0xAA-poisoned != MAGIC)

    k_one<<<NBLOCKS, 1024, 0, stream>>>(hidden, obs2, W, b, out, Sh, Wb, flags);
}

// Round 9
// 99.789 us; speedup vs baseline: 1.1600x; 1.1600x over previous
//
#include <hip/hip_runtime.h>
#include <math.h>

#define N_AGENTS 1024
#define HIDDEN   128
#define GRIDSZ   32
#define NCELLS   1024
#define KDIM     2048

typedef __attribute__((ext_vector_type(8))) short short8;   // 8 bf16 = 4 VGPRs
typedef __attribute__((ext_vector_type(4))) float floatx4;  // MFMA accumulator

static __device__ __forceinline__ ushort f2bf(float x) {   // RNE fp32->bf16
    union { float f; unsigned u; } v; v.f = x;
    return (ushort)((v.u + 0x7fffu + ((v.u >> 16) & 1u)) >> 16);
}

static __device__ __forceinline__ unsigned cvt2(float lo, float hi) {   // packed RNE pair
    return (unsigned)f2bf(lo) | ((unsigned)f2bf(hi) << 16);
}

// One block per 16-agent m-tile (64 blocks x 1024 thr), fully self-sufficient:
// no workspace, no fences, no inter-block deps. Each block rebuilds the Sh
// table (hidden is L2-resident; 4 MB/XCD total) and converts its W stream
// fp32->bf16 in-register. Scan+pooling once per m-tile.
__global__ __launch_bounds__(1024, 1) void k_one(
        const float* __restrict__ hidden, const float* __restrict__ obs2,
        const float* __restrict__ W, const float* __restrict__ bias,
        float* __restrict__ out) {
    __shared__ float2 spos[N_AGENTS];                   // 8 KB
    __shared__ float4 ssh[N_AGENTS];                    // 16 KB
    __shared__ int win[16][NCELLS];                     // 64 KB (reused as pbuf)
    __shared__ __align__(16) ushort Gs[256 * 16 * 8];   // 64 KB: [kblk][row][8] bf16

    const int tid = threadIdx.x;
    const int mt = blockIdx.x;
    const int ibase = mt * 16;

    // ---- P0: positions, full Sh table (hidden read once per block), win init
    spos[tid] = ((const float2*)obs2)[tid];
    {
        int4* wl = (int4*)&win[0][0];
        int4 m1 = {-1, -1, -1, -1};
#pragma unroll
        for (int q = 0; q < 4; ++q) wl[q * 1024 + tid] = m1;
    }
#pragma unroll
    for (int q = 0; q < 4; ++q) {
        int idx = q * 1024 + tid;         // entry (j, c); lanes 0-3 share row j
        int j = idx >> 2, c = idx & 3;
        const float* h = hidden + j * HIDDEN + c * 8;
        float s = 0.f;
#pragma unroll
        for (int u = 0; u < 4; ++u) {     // Sh[j][c] = sum of 32 strided floats
            float4 a = *(const float4*)(h + u * 32);
            float4 b = *(const float4*)(h + u * 32 + 4);
            s += a.x + a.y + a.z + a.w + b.x + b.y + b.z + b.w;
        }
        ((float*)&ssh[j])[c] = s;
    }
    __syncthreads();

    // ---- P1: one j-scan fills 16 winner grids (set semantics == max j)
    float2 pi[16];
#pragma unroll
    for (int a = 0; a < 16; ++a) pi[a] = spos[ibase + a];
    {
        float2 pj = spos[tid];   // thread == j
        if (!isnan(pj.x)) {
#pragma unroll
            for (int a = 0; a < 16; ++a) {
                if (tid == ibase + a) continue;
                // exact reference fp32 math: /0.125 == *8 (exact pow2), then +16
                float rx = (pj.x - pi[a].x) * 8.0f + 16.0f;   // NaN pi -> cmps false
                float ry = (pj.y - pi[a].y) * 8.0f + 16.0f;
                if (rx >= 0.f && rx < 32.f && ry >= 0.f && ry < 32.f)
                    atomicMax(&win[a][(int)rx * GRIDSZ + (int)ry], tid);
            }
        }
    }
    __syncthreads();

    // ---- P2: pooling -> bf16 A-tile in LDS, layout [kblk=k/8][row=a][8 elems]
#pragma unroll
    for (int q = 0; q < 8; ++q) {
        int task = q * 1024 + tid;
        int a = task & 15, p = task >> 4;   // cell-pair p, local agent a
        int w0 = win[a][2 * p], w1 = win[a][2 * p + 1];
        float4 v = {0.f, 0.f, 0.f, 0.f};
        if (w0 >= 0) { float4 s = ssh[w0]; v.x += s.x; v.y += s.y; v.z += s.z; v.w += s.w; }
        if (w1 >= 0) { float4 s = ssh[w1]; v.x += s.x; v.y += s.y; v.z += s.z; v.w += s.w; }
        ushort4 u;
        u.x = f2bf(v.x); u.y = f2bf(v.y); u.z = f2bf(v.z); u.w = f2bf(v.w);
        // k = 4p + [0..3]  ->  kblk = p>>1, e = (p&1)*4 + [0..3]
        *(ushort4*)(Gs + ((p >> 1) * 16 + a) * 8 + (p & 1) * 4) = u;
    }
    __syncthreads();

    // ---- P3: MFMA. wave w: n-tile ntl = w>>1, k-splits {ks2, ks2+1} summed
    // in-register. A from LDS Gs; B = fp32 W from L2, packed-cvt to bf16.
    const int wv = tid >> 6, lane = tid & 63;
    const int ntl = wv >> 1, ks2 = (wv & 1) * 2;
    const int r16 = lane & 15, quad = lane >> 4;
    const int col = ntl * 16 + r16;
    floatx4 accs = {0.f, 0.f, 0.f, 0.f};
#pragma unroll
    for (int kh = 0; kh < 2; ++kh) {
        const int ks = ks2 + kh;
        const float* Wp = W + (size_t)col * KDIM + ks * 512 + quad * 8;
        floatx4 acc = {0.f, 0.f, 0.f, 0.f};
#pragma unroll
        for (int kb = 0; kb < 16; ++kb) {
            short8 av = *(const short8*)(Gs + ((ks * 64 + kb * 4 + quad) * 16 + r16) * 8);
            float4 wa = *(const float4*)(Wp + kb * 32);
            float4 wb = *(const float4*)(Wp + kb * 32 + 4);
            union { short8 s; unsigned u[4]; } bv;
            bv.u[0] = cvt2(wa.x, wa.y);
            bv.u[1] = cvt2(wa.z, wa.w);
            bv.u[2] = cvt2(wb.x, wb.y);
            bv.u[3] = cvt2(wb.z, wb.w);
            acc = __builtin_amdgcn_mfma_f32_16x16x32_bf16(av, bv.s, acc, 0, 0, 0);
        }
        accs[0] += acc[0]; accs[1] += acc[1]; accs[2] += acc[2]; accs[3] += acc[3];
    }

    // ---- P4: 2-way cross-wave k-reduce (pbuf aliases dead win), bias, store
    float* pbuf = (float*)&win[0][0];   // 16 KB used
    *(floatx4*)&pbuf[tid * 4] = accs;
    __syncthreads();
    if ((wv & 1) == 0) {
        floatx4 pv = *(const floatx4*)&pbuf[((wv + 1) * 64 + lane) * 4];
        accs[0] += pv[0]; accs[1] += pv[1]; accs[2] += pv[2]; accs[3] += pv[3];
        float bc = bias[col];
        // C/D layout (m89-verified): col = lane&15, row = quad*4 + reg
#pragma unroll
        for (int r = 0; r < 4; ++r)
            out[(size_t)(ibase + quad * 4 + r) * HIDDEN + col] = accs[r] + bc;
    }
}

extern "C" void kernel_launch(void* const* d_in, const int* in_sizes, int n_in,
                              void* d_out, int out_size, void* d_ws, size_t ws_size,
                              hipStream_t stream) {
    const float* hidden = (const float*)d_in[0];
    // d_in[1] = obs1 — unused by the reference
    const float* obs2   = (const float*)d_in[2];
    const float* W      = (const float*)d_in[3];
    const float* b      = (const float*)d_in[4];
    float* out = (float*)d_out;
    (void)d_ws; (void)ws_size;

    k_one<<<64, 1024, 0, stream>>>(hidden, obs2, W, b, out);
}

// Round 10
// 76.293 us; speedup vs baseline: 1.5173x; 1.3080x over previous
//
#include <hip/hip_runtime.h>
#include <math.h>

#define N_AGENTS 1024
#define HIDDEN   128
#define GRIDSZ   32
#define NCELLS   1024
#define KDIM     2048

typedef __attribute__((ext_vector_type(8))) short short8;   // 8 bf16 = 4 VGPRs
typedef __attribute__((ext_vector_type(4))) float floatx4;  // MFMA accumulator

static __device__ __forceinline__ ushort f2bf(float x) {   // RNE fp32->bf16
    union { float f; unsigned u; } v; v.f = x;
    return (ushort)((v.u + 0x7fffu + ((v.u >> 16) & 1u)) >> 16);
}

static __device__ __forceinline__ unsigned cvt2(float lo, float hi) {   // packed RNE pair
    return (unsigned)f2bf(lo) | ((unsigned)f2bf(hi) << 16);
}

// K1: block = (m-tile, half): winner scan for 8 agents (each agent scanned ONCE
// grid-wide — no ng duplication), winners -> global winG. Also 1/128 slices of
// W->bf16 cvt, Sh table, out=bias init.
__global__ __launch_bounds__(1024) void k_scan(
        const float* __restrict__ hidden, const float* __restrict__ obs2,
        const float* __restrict__ W, const float* __restrict__ bias,
        float* __restrict__ Sh, ushort* __restrict__ Wb,
        int* __restrict__ winG, float* __restrict__ out) {
    __shared__ int win[8][NCELLS];   // 32 KB
    const int tid = threadIdx.x;
    const int mt = blockIdx.x >> 1, half = blockIdx.x & 1;
    const int abase = mt * 16 + half * 8;

    {   // Wb slice: 2048 bf16 (coalesced float2 -> packed store)
        float2 w = ((const float2*)W)[blockIdx.x * 1024 + tid];
        ((unsigned*)Wb)[blockIdx.x * 1024 + tid] = cvt2(w.x, w.y);
    }
    out[blockIdx.x * 1024 + tid] = bias[tid & (HIDDEN - 1)];   // bias init slice
    if (tid < 32) {   // Sh slice: Sh[j][c] = sum over d with ((d>>3)&3)==c
        int j = abase + (tid >> 2), c = tid & 3;
        const float* h = hidden + j * HIDDEN + c * 8;
        float s = 0.f;
#pragma unroll
        for (int u = 0; u < 4; ++u) {
            float4 a = *(const float4*)(h + u * 32);
            float4 b = *(const float4*)(h + u * 32 + 4);
            s += a.x + a.y + a.z + a.w + b.x + b.y + b.z + b.w;
        }
        Sh[j * 4 + c] = s;
    }
    {   // win init
        int4* wl = (int4*)&win[0][0];
        int4 m1 = {-1, -1, -1, -1};
#pragma unroll
        for (int q = 0; q < 2; ++q) wl[q * 1024 + tid] = m1;
    }
    __syncthreads();

    // scan: thread == j; set semantics == max j
    const float2* o2 = (const float2*)obs2;
    float2 pi[8];
#pragma unroll
    for (int a = 0; a < 8; ++a) pi[a] = o2[abase + a];
    float2 pj = o2[tid];
    if (!isnan(pj.x)) {
#pragma unroll
        for (int a = 0; a < 8; ++a) {
            if (tid == abase + a) continue;
            // exact reference fp32 math: /0.125 == *8 (exact pow2), then +16
            float rx = (pj.x - pi[a].x) * 8.0f + 16.0f;   // NaN pi -> cmps false
            float ry = (pj.y - pi[a].y) * 8.0f + 16.0f;
            if (rx >= 0.f && rx < 32.f && ry >= 0.f && ry < 32.f)
                atomicMax(&win[a][(int)rx * GRIDSZ + (int)ry], tid);
        }
    }
    __syncthreads();

    {   // dump winners: winG[mt*16384 + (half*8 + a)*1024 + c]
        int4* dst = (int4*)(winG + mt * 16384 + half * 8192);
        const int4* src = (const int4*)&win[0][0];
#pragma unroll
        for (int q = 0; q < 2; ++q) dst[q * 1024 + tid] = src[q * 1024 + tid];
    }
}

// K2: block = (mt, ng of 32 cols); only 16 KB LDS (ssh) -> high occupancy.
// A-frag built fused in the MFMA loop: win4 from global (VMEM/L2), ssh
// gathers from LDS, cvt in-register. B = bf16 Wb from L2. atomicAdd to
// bias-preset out (4 contenders per address).
__global__ __launch_bounds__(512) void k_gemm(
        const float4* __restrict__ Sh4, const ushort* __restrict__ Wb,
        const int* __restrict__ winG, float* __restrict__ out) {
    __shared__ float4 ssh[N_AGENTS];   // 16 KB
    const int tid = threadIdx.x;
    const int mt = blockIdx.x >> 2, ng = blockIdx.x & 3;
    const int ibase = mt * 16;
    ssh[tid] = Sh4[tid];
    ssh[tid + 512] = Sh4[tid + 512];
    __syncthreads();

    const int wv = tid >> 6, lane = tid & 63;
    const int ntl = wv >> 2, ks = wv & 3;          // 2 n-tiles x 4 k-splits
    const int r16 = lane & 15, quad = lane >> 4;
    const int col = ng * 32 + ntl * 16 + r16;
    const ushort* Wp = Wb + (size_t)col * KDIM + ks * 512 + quad * 8;
    const int* wrow = winG + mt * 16384 + r16 * 1024;   // winners, row r16
    floatx4 acc = {0.f, 0.f, 0.f, 0.f};
#pragma unroll
    for (int kb = 0; kb < 16; ++kb) {
        int k0 = ks * 512 + kb * 32 + quad * 8;
        int4 w4 = *(const int4*)(wrow + (k0 >> 1));   // cells 2p0..2p0+3
        float4 v0 = {0.f, 0.f, 0.f, 0.f}, v1 = {0.f, 0.f, 0.f, 0.f};
        if (w4.x >= 0) { float4 s = ssh[w4.x]; v0.x += s.x; v0.y += s.y; v0.z += s.z; v0.w += s.w; }
        if (w4.y >= 0) { float4 s = ssh[w4.y]; v0.x += s.x; v0.y += s.y; v0.z += s.z; v0.w += s.w; }
        if (w4.z >= 0) { float4 s = ssh[w4.z]; v1.x += s.x; v1.y += s.y; v1.z += s.z; v1.w += s.w; }
        if (w4.w >= 0) { float4 s = ssh[w4.w]; v1.x += s.x; v1.y += s.y; v1.z += s.z; v1.w += s.w; }
        union { short8 s; unsigned u[4]; } av;
        av.u[0] = cvt2(v0.x, v0.y);
        av.u[1] = cvt2(v0.z, v0.w);
        av.u[2] = cvt2(v1.x, v1.y);
        av.u[3] = cvt2(v1.z, v1.w);
        short8 bv = *(const short8*)(Wp + kb * 32);
        acc = __builtin_amdgcn_mfma_f32_16x16x32_bf16(av.s, bv, acc, 0, 0, 0);
    }
    // C/D layout (m89-verified): col = lane&15, row = quad*4 + reg
    float* o = out + (size_t)(ibase + quad * 4) * HIDDEN + col;
#pragma unroll
    for (int r = 0; r < 4; ++r) atomicAdd(&o[(size_t)r * HIDDEN], acc[r]);
}

extern "C" void kernel_launch(void* const* d_in, const int* in_sizes, int n_in,
                              void* d_out, int out_size, void* d_ws, size_t ws_size,
                              hipStream_t stream) {
    const float* hidden = (const float*)d_in[0];
    // d_in[1] = obs1 — unused by the reference
    const float* obs2   = (const float*)d_in[2];
    const float* W      = (const float*)d_in[3];
    const float* b      = (const float*)d_in[4];
    float* out = (float*)d_out;

    float*  Sh   = (float*) d_ws;                        // 16 KB
    ushort* Wb   = (ushort*)((char*)d_ws + 65536);       // 512 KB bf16 W
    int*    winG = (int*)   ((char*)d_ws + (1u << 20));  // 4 MB winner arrays

    k_scan<<<128, 1024, 0, stream>>>(hidden, obs2, W, b, Sh, Wb, winG, out);
    k_gemm<<<256,  512, 0, stream>>>((const float4*)Sh, Wb, winG, out);
}